// Round 7
// baseline (399.375 us; speedup 1.0000x reference)
//
#include <hip/hip_runtime.h>
#include <hip/hip_cooperative_groups.h>

namespace cg = cooperative_groups;

// Problem constants (fixed by the dataset)
constexpr int S_  = 4096;
constexpr int B_  = 2;
constexpr int C_  = 256;
constexpr int H_  = 8;
constexpr int E_  = 131072;
constexpr int CC_ = 32;
constexpr int MR  = S_ * B_;   // 8192 rows for all GEMMs

typedef __attribute__((ext_vector_type(8))) short bf16x8_t;
typedef __attribute__((ext_vector_type(4))) float f32x4_t;

__device__ __forceinline__ unsigned short f2bf(float f) {
    unsigned int u = __float_as_uint(f);
    u += 0x7fffu + ((u >> 16) & 1u);   // round-to-nearest-even
    return (unsigned short)(u >> 16);
}
__device__ __forceinline__ float bflo(unsigned int u) { return __uint_as_float(u << 16); }
__device__ __forceinline__ float bfhi(unsigned int u) { return __uint_as_float(u & 0xffff0000u); }

__device__ __forceinline__ void cast8(const float* __restrict__ src, unsigned short* __restrict__ dst, int i) {
    const float4* s = (const float4*)src + (size_t)i * 2;
    float4 a = s[0], b = s[1];
    uint4 o;
    o.x = (unsigned)f2bf(a.x) | ((unsigned)f2bf(a.y) << 16);
    o.y = (unsigned)f2bf(a.z) | ((unsigned)f2bf(a.w) << 16);
    o.z = (unsigned)f2bf(b.x) | ((unsigned)f2bf(b.y) << 16);
    o.w = (unsigned)f2bf(b.z) | ((unsigned)f2bf(b.w) << 16);
    *((uint4*)dst + i) = o;
}

// ================= shared phase bodies (used by mega kernel AND fallback) =================

// ---- scan: 256 threads, 16 bins/thread ----
__device__ __forceinline__ void scan_body(const int* __restrict__ count,
                                          int* __restrict__ base, int* __restrict__ cursor,
                                          int* wsums /*>=4 ints LDS*/) {
    const int t = threadIdx.x, lane = t & 63, w = t >> 6;
    int c[16]; int s = 0;
#pragma unroll
    for (int i = 0; i < 16; ++i) { c[i] = count[t * 16 + i]; s += c[i]; }
    int x = s;
#pragma unroll
    for (int off = 1; off < 64; off <<= 1) {
        int y = __shfl_up(x, off);
        if (lane >= off) x += y;
    }
    if (lane == 63) wsums[w] = x;
    __syncthreads();
    if (t == 0) {
        int run = 0;
#pragma unroll
        for (int i = 0; i < 4; ++i) { int v = wsums[i]; wsums[i] = run; run += v; }
        base[S_] = run;
    }
    __syncthreads();
    int run = x - s + wsums[w];
#pragma unroll
    for (int i = 0; i < 16; ++i) {
        base[t * 16 + i] = run; cursor[t * 16 + i] = run; run += c[i];
    }
}

// ---- one QKV gemm unit: u in [0,516) = 12 n-blocks x 43 m-groups ----
__device__ __forceinline__ void qkv_unit(
        int u, int tid,
        const unsigned short* __restrict__ xb, const unsigned short* __restrict__ Wb,
        const float* __restrict__ bq, const float* __restrict__ bk, const float* __restrict__ bv,
        unsigned short* __restrict__ qb, unsigned short* __restrict__ kvb,
        unsigned short (*As)[264]) {
    const int nb = u % 12, mg = u / 12;
    const int lane = tid & 63, wave = tid >> 6;
    const int l16 = lane & 15, quad = lane >> 4;
    const int z = nb >> 2;
    const int colz = ((nb & 3) << 6) + (wave << 4);

    const unsigned short* Wrow = Wb + (size_t)z * (C_ * C_) + (size_t)(colz + l16) * C_;
    bf16x8_t breg[8];
#pragma unroll
    for (int ks = 0; ks < 8; ++ks)
        breg[ks] = *(const bf16x8_t*)(Wrow + ks * 32 + quad * 8);

    const float* bias = (z == 0) ? bq : (z == 1) ? bk : bv;
    const float bcol = bias[colz + l16];
    unsigned short* ob = (z == 0) ? qb : kvb;
    const int ostr = (z == 0) ? 256 : 512;
    const int ocol = ((z == 2) ? 256 : 0) + colz + l16;

    const int c0 = (mg * 128) / 43, c1 = ((mg + 1) * 128) / 43;
    for (int c = c0; c < c1; ++c) {
        const int mbase = c * 64;
        __syncthreads();
#pragma unroll
        for (int it = 0; it < 8; ++it) {
            int l = it * 256 + tid;
            int r = l >> 5, cc = (l & 31) << 3;
            *(uint4*)&As[r][cc] = *(const uint4*)&xb[(size_t)(mbase + r) * C_ + cc];
        }
        __syncthreads();
#pragma unroll
        for (int mt = 0; mt < 4; ++mt) {
            f32x4_t acc = {0.f, 0.f, 0.f, 0.f};
#pragma unroll
            for (int ks = 0; ks < 8; ++ks) {
                bf16x8_t a = *(const bf16x8_t*)&As[mt * 16 + l16][ks * 32 + quad * 8];
                acc = __builtin_amdgcn_mfma_f32_16x16x32_bf16(a, breg[ks], acc, 0, 0, 0);
            }
            const int row0 = mbase + mt * 16 + quad * 4;
#pragma unroll
            for (int r = 0; r < 4; ++r)
                ob[(size_t)(row0 + r) * ostr + ocol] = f2bf(acc[r] + bcol);
        }
    }
}

// ---- attention for one row-pair rb in [0,2048): 4 waves = 2 rows x 2 parts ----
__device__ __forceinline__ void attn_pair(
        int rb, int tid,
        const unsigned short* __restrict__ qb, const unsigned short* __restrict__ kvb,
        const int* __restrict__ base, const int* __restrict__ koff,
        unsigned short* __restrict__ attnb, float* redbuf /*2*64*9 floats LDS*/) {
    const int lane = tid & 63, wave = tid >> 6;
    const int rw = wave >> 1, part = wave & 1;
    const int s = rb * 2 + rw;
    const int half = lane >> 5, hl = lane & 31;
    const int e0 = __builtin_amdgcn_readfirstlane(base[s]);
    const int e1 = __builtin_amdgcn_readfirstlane(base[s + 1]);

    const uint4 qq = *((const uint4*)(qb + (size_t)(s * 2 + half) * C_) + hl);
    const float q0 = bflo(qq.x), q1 = bfhi(qq.x), q2 = bflo(qq.y), q3 = bfhi(qq.y);
    const float q4 = bflo(qq.z), q5 = bfhi(qq.z), q6 = bflo(qq.w), q7 = bfhi(qq.w);

    float a0 = 0.f, a1 = 0.f, a2 = 0.f, a3 = 0.f, a4 = 0.f, a5 = 0.f, a6 = 0.f, a7 = 0.f;
    float wsum = 0.f;
    const float scale = 0.17677669529663687f;   // 1/sqrt(32)

    auto edge = [&](const uint4& kk, const uint4& vv) {
        float p = q0 * bflo(kk.x) + q1 * bfhi(kk.x)
                + q2 * bflo(kk.y) + q3 * bfhi(kk.y)
                + q4 * bflo(kk.z) + q5 * bfhi(kk.z)
                + q6 * bflo(kk.w) + q7 * bfhi(kk.w);
        p += __shfl_xor(p, 1);
        p += __shfl_xor(p, 2);
        const float w = __expf(p * scale);
        a0 = fmaf(w, bflo(vv.x), a0); a1 = fmaf(w, bfhi(vv.x), a1);
        a2 = fmaf(w, bflo(vv.y), a2); a3 = fmaf(w, bfhi(vv.y), a3);
        a4 = fmaf(w, bflo(vv.z), a4); a5 = fmaf(w, bfhi(vv.z), a5);
        a6 = fmaf(w, bflo(vv.w), a6); a7 = fmaf(w, bfhi(vv.w), a7);
        wsum += w;
    };
    auto fetch = [&](int my, int t, uint4& kk, uint4& vv) {
        int o = __builtin_amdgcn_readlane(my, part + 2 * t);
        const uint4* p = (const uint4*)(kvb + o + half * 512);
        kk = p[hl]; vv = p[32 + hl];
    };

    for (int b0 = e0; b0 < e1; b0 += 64) {
        const int m = min(64, e1 - b0);
        const int my = koff[b0 + ((lane < m) ? lane : 0)];
        const int nm = (m > part) ? ((m - part + 1) >> 1) : 0;
        uint4 kka = {}, vva = {}, kkb = {}, vvb = {};
        if (nm > 0) fetch(my, 0, kka, vva);
        if (nm > 1) fetch(my, 1, kkb, vvb);
        int t = 0;
        for (; t + 3 < nm; t += 2) {
            edge(kka, vva);
            fetch(my, t + 2, kka, vva);
            edge(kkb, vvb);
            fetch(my, t + 3, kkb, vvb);
        }
        if (t < nm)     edge(kka, vva);
        if (t + 1 < nm) edge(kkb, vvb);
        if (t + 2 < nm) { fetch(my, t + 2, kka, vva); edge(kka, vva); }
    }

    float* r = redbuf + (size_t)(rw * 64 + lane) * 9;
    if (part == 1) {
        r[0] = a0; r[1] = a1; r[2] = a2; r[3] = a3;
        r[4] = a4; r[5] = a5; r[6] = a6; r[7] = a7; r[8] = wsum;
    }
    __syncthreads();
    if (part == 0) {
        a0 += r[0]; a1 += r[1]; a2 += r[2]; a3 += r[3];
        a4 += r[4]; a5 += r[5]; a6 += r[6]; a7 += r[7]; wsum += r[8];
        const float inv = 1.0f / wsum;
        uint4 o;
        o.x = (unsigned)f2bf(a0 * inv) | ((unsigned)f2bf(a1 * inv) << 16);
        o.y = (unsigned)f2bf(a2 * inv) | ((unsigned)f2bf(a3 * inv) << 16);
        o.z = (unsigned)f2bf(a4 * inv) | ((unsigned)f2bf(a5 * inv) << 16);
        o.w = (unsigned)f2bf(a6 * inv) | ((unsigned)f2bf(a7 * inv) << 16);
        *((uint4*)(attnb + (size_t)(s * 2 + half) * C_) + hl) = o;
    }
}

// ---- one proj unit: u in [0,512) = 4 n-blocks x 128 m-groups ----
__device__ __forceinline__ void proj_unit(
        int u, int tid,
        const unsigned short* __restrict__ attnb, const unsigned short* __restrict__ Wxb,
        const float* __restrict__ bx, float* __restrict__ out,
        unsigned short (*As)[264]) {
    const int nb = u & 3, mg = u >> 2;
    const int lane = tid & 63, wave = tid >> 6;
    const int l16 = lane & 15, quad = lane >> 4;
    const int colz = (nb << 6) + (wave << 4);

    const unsigned short* Wrow = Wxb + (size_t)(colz + l16) * C_;
    bf16x8_t breg[8];
#pragma unroll
    for (int ks = 0; ks < 8; ++ks)
        breg[ks] = *(const bf16x8_t*)(Wrow + ks * 32 + quad * 8);
    const float bcol = bx[colz + l16];
    const int ocol = colz + l16;

    const int mbase = mg * 64;
#pragma unroll
    for (int it = 0; it < 8; ++it) {
        int l = it * 256 + tid;
        int r = l >> 5, cc = (l & 31) << 3;
        *(uint4*)&As[r][cc] = *(const uint4*)&attnb[(size_t)(mbase + r) * C_ + cc];
    }
    __syncthreads();
#pragma unroll
    for (int mt = 0; mt < 4; ++mt) {
        f32x4_t acc = {0.f, 0.f, 0.f, 0.f};
#pragma unroll
        for (int ks = 0; ks < 8; ++ks) {
            bf16x8_t a = *(const bf16x8_t*)&As[mt * 16 + l16][ks * 32 + quad * 8];
            acc = __builtin_amdgcn_mfma_f32_16x16x32_bf16(a, breg[ks], acc, 0, 0, 0);
        }
        const int row0 = mbase + mt * 16 + quad * 4;
#pragma unroll
        for (int r = 0; r < 4; ++r)
            out[(size_t)(row0 + r) * C_ + ocol] = acc[r] + bcol;
    }
}

// ================= cooperative mega-kernel: 512 blocks x 256 threads =================

__global__ __launch_bounds__(256, 2) void mega_kernel(
        const float* __restrict__ x, const int* __restrict__ q_id, const int* __restrict__ k_id,
        const float* __restrict__ Wq, const float* __restrict__ bq,
        const float* __restrict__ Wk, const float* __restrict__ bk,
        const float* __restrict__ Wv, const float* __restrict__ bv,
        const float* __restrict__ Wx, const float* __restrict__ bx,
        float* __restrict__ out,
        unsigned short* __restrict__ xb, unsigned short* __restrict__ qb,
        unsigned short* __restrict__ kvb, unsigned short* __restrict__ attnb,
        unsigned short* __restrict__ Wb,
        int* __restrict__ count, int* __restrict__ base, int* __restrict__ cursor,
        int* __restrict__ koff) {
    cg::grid_group grid = cg::this_grid();
    __shared__ __align__(16) char smem[64 * 264 * 2];   // 33792 B, reused per phase
    const int bid = blockIdx.x, tid = threadIdx.x;
    const int gid = bid * 256 + tid;                     // 0..131071

    // ---- P0: cast x (2 chunks/thread), cast W, histogram
    cast8(x, xb, gid);
    cast8(x, xb, gid + 131072);
    if (gid < 32768) {
        int z = gid >> 13;
        const float* src = (z == 0) ? Wq : (z == 1) ? Wk : (z == 2) ? Wv : Wx;
        cast8(src, Wb + (size_t)z * (C_ * C_), gid & 8191);
    }
    atomicAdd(&count[q_id[gid]], 1);
    grid.sync();

    // ---- P1: scan (block 511) + QKV gemm (units 0..515, strided by 512)
    if (bid == 511) scan_body(count, base, cursor, (int*)smem);
    for (int u = bid; u < 516; u += 512)
        qkv_unit(u, tid, xb, Wb, bq, bk, bv, qb, kvb, (unsigned short(*)[264])smem);
    grid.sync();

    // ---- P2: scatter (counting sort payload)
    {
        int pos = atomicAdd(&cursor[q_id[gid]], 1);
        koff[pos] = k_id[gid] << 10;
    }
    grid.sync();

    // ---- P3: attention, 2048 row-pairs over 512 blocks (4 iterations)
    for (int rb = bid; rb < 2048; rb += 512) {
        __syncthreads();
        attn_pair(rb, tid, qb, kvb, base, koff, attnb, (float*)smem);
    }
    grid.sync();

    // ---- P4: projection (512 units, one per block)
    proj_unit(bid, tid, attnb, Wb + (size_t)3 * (C_ * C_), bx, out,
              (unsigned short(*)[264])smem);
}

// ================= fallback kernels (= proven R6 path) =================

__global__ __launch_bounds__(256) void fb_prep(
        const int* __restrict__ q_id, int* __restrict__ count,
        const float* __restrict__ x, unsigned short* __restrict__ xb,
        const float* __restrict__ Wq, const float* __restrict__ Wk,
        const float* __restrict__ Wv, const float* __restrict__ Wx,
        unsigned short* __restrict__ Wb) {
    const int bid = blockIdx.x, tid = threadIdx.x;
    if (bid < 512) {
        atomicAdd(&count[q_id[bid * 256 + tid]], 1);
    } else if (bid < 1536) {
        cast8(x, xb, (bid - 512) * 256 + tid);
    } else {
        int idx = bid - 1536;
        int z = idx >> 5;
        const float* src = (z == 0) ? Wq : (z == 1) ? Wk : (z == 2) ? Wv : Wx;
        cast8(src, Wb + (size_t)z * (C_ * C_), (idx & 31) * 256 + tid);
    }
}

__global__ __launch_bounds__(256) void fb_scan(const int* __restrict__ count,
                                               int* __restrict__ base,
                                               int* __restrict__ cursor) {
    __shared__ int wsums[4];
    scan_body(count, base, cursor, wsums);
}

__global__ __launch_bounds__(256) void fb_scatter_qkv(
        const int* __restrict__ q_id, const int* __restrict__ k_id,
        int* __restrict__ cursor, int* __restrict__ koff,
        const unsigned short* __restrict__ xb, const unsigned short* __restrict__ Wb,
        const float* __restrict__ bq, const float* __restrict__ bk, const float* __restrict__ bv,
        unsigned short* __restrict__ qb, unsigned short* __restrict__ kvb) {
    __shared__ __align__(16) unsigned short As[64][264];
    const int bid = blockIdx.x, tid = threadIdx.x;
    if (bid < 512) {
        int e = bid * 256 + tid;
        int pos = atomicAdd(&cursor[q_id[e]], 1);
        koff[pos] = k_id[e] << 10;
        return;
    }
    qkv_unit(bid - 512, tid, xb, Wb, bq, bk, bv, qb, kvb, As);
}

__global__ __launch_bounds__(256) void fb_attn(
        const unsigned short* __restrict__ qb, const unsigned short* __restrict__ kvb,
        const int* __restrict__ base, const int* __restrict__ koff,
        unsigned short* __restrict__ attnb) {
    __shared__ float red[2 * 64 * 9];
    attn_pair(blockIdx.x, threadIdx.x, qb, kvb, base, koff, attnb, red);
}

__global__ __launch_bounds__(256) void fb_proj(
        const unsigned short* __restrict__ attnb, const unsigned short* __restrict__ Wxb,
        const float* __restrict__ bx, float* __restrict__ out) {
    __shared__ __align__(16) unsigned short As[64][264];
    proj_unit(blockIdx.x, threadIdx.x, attnb, Wxb, bx, out, As);
}

// ================= launch =================

extern "C" void kernel_launch(void* const* d_in, const int* in_sizes, int n_in,
                              void* d_out, int out_size, void* d_ws, size_t ws_size,
                              hipStream_t stream) {
    const float* x  = (const float*)d_in[0];
    const int* q_id = (const int*)d_in[1];
    const int* k_id = (const int*)d_in[2];
    const float* Wq = (const float*)d_in[3];
    const float* bq = (const float*)d_in[4];
    const float* Wk = (const float*)d_in[5];
    const float* bk = (const float*)d_in[6];
    const float* Wv = (const float*)d_in[7];
    const float* bv = (const float*)d_in[8];
    const float* Wx = (const float*)d_in[9];
    const float* bx = (const float*)d_in[10];
    float* out = (float*)d_out;

    char* ws = (char*)d_ws;
    unsigned short* xb    = (unsigned short*)ws;   ws += (size_t)MR * C_ * 2;
    unsigned short* qb    = (unsigned short*)ws;   ws += (size_t)MR * C_ * 2;
    unsigned short* kvb   = (unsigned short*)ws;   ws += (size_t)MR * 512 * 2;
    unsigned short* attnb = (unsigned short*)ws;   ws += (size_t)MR * C_ * 2;
    unsigned short* Wb    = (unsigned short*)ws;   ws += (size_t)4 * C_ * C_ * 2;
    int* count  = (int*)ws;                        ws += S_ * 4;
    int* base   = (int*)ws;                        ws += (S_ + 1) * 4;
    int* cursor = (int*)ws;                        ws += S_ * 4;
    int* koff   = (int*)ws;

    hipMemsetAsync(count, 0, S_ * sizeof(int), stream);

    void* args[] = {
        (void*)&x, (void*)&q_id, (void*)&k_id,
        (void*)&Wq, (void*)&bq, (void*)&Wk, (void*)&bk,
        (void*)&Wv, (void*)&bv, (void*)&Wx, (void*)&bx,
        (void*)&out,
        (void*)&xb, (void*)&qb, (void*)&kvb, (void*)&attnb, (void*)&Wb,
        (void*)&count, (void*)&base, (void*)&cursor, (void*)&koff,
    };
    hipError_t err = hipLaunchCooperativeKernel((const void*)mega_kernel,
                                                dim3(512), dim3(256), args, 0, stream);
    if (err != hipSuccess) {
        // fallback: proven 5-kernel path (R6)
        fb_prep<<<1664, 256, 0, stream>>>(q_id, count, x, xb, Wq, Wk, Wv, Wx, Wb);
        fb_scan<<<1, 256, 0, stream>>>(count, base, cursor);
        fb_scatter_qkv<<<1028, 256, 0, stream>>>(q_id, k_id, cursor, koff,
                                                 xb, Wb, bq, bk, bv, qb, kvb);
        fb_attn<<<2048, 256, 0, stream>>>(qb, kvb, base, koff, attnb);
        fb_proj<<<512, 256, 0, stream>>>(attnb, Wb + (size_t)3 * C_ * C_, bx, out);
    }
}

// Round 8
// 148.364 us; speedup vs baseline: 2.6919x; 2.6919x over previous
//
#include <hip/hip_runtime.h>

// Problem constants (fixed by the dataset)
constexpr int S_  = 4096;
constexpr int B_  = 2;
constexpr int C_  = 256;
constexpr int H_  = 8;
constexpr int E_  = 131072;
constexpr int CC_ = 32;
constexpr int MR  = S_ * B_;   // 8192 rows for all GEMMs

typedef __attribute__((ext_vector_type(8))) short bf16x8_t;
typedef __attribute__((ext_vector_type(4))) float f32x4_t;

__device__ __forceinline__ unsigned short f2bf(float f) {
    unsigned int u = __float_as_uint(f);
    u += 0x7fffu + ((u >> 16) & 1u);   // round-to-nearest-even
    return (unsigned short)(u >> 16);
}
__device__ __forceinline__ float bflo(unsigned int u) { return __uint_as_float(u << 16); }
__device__ __forceinline__ float bfhi(unsigned int u) { return __uint_as_float(u & 0xffff0000u); }

// ---- fp8 e4m3 (OCP) encode/decode: HW cvt if available, software fallback ----
__device__ __forceinline__ unsigned char f2fp8(float f) {
#if __has_builtin(__builtin_amdgcn_cvt_pk_fp8_f32)
    return (unsigned char)(__builtin_amdgcn_cvt_pk_fp8_f32(f, f, 0, false) & 0xff);
#else
    unsigned u = __float_as_uint(f);
    unsigned s = (u >> 31) << 7;
    int e = (int)((u >> 23) & 0xff) - 127;
    unsigned m = u & 0x7fffff;
    if (e < -9) return (unsigned char)s;
    if (e < -6) {
        float a = __uint_as_float(u & 0x7fffffff);
        unsigned q = (unsigned)__float2int_rn(a * 512.0f);
        return (unsigned char)(s | q);
    }
    unsigned mr = (m + 0x7ffffu + ((m >> 20) & 1u)) >> 20;
    if (mr >= 8) { mr = 0; ++e; }
    if (e > 8) return (unsigned char)(s | 0x7e);
    return (unsigned char)(s | ((unsigned)(e + 7) << 3) | mr);
#endif
}

__device__ __forceinline__ void fp8x4_dec(unsigned w, float* d) {
#if __has_builtin(__builtin_amdgcn_cvt_pk_f32_fp8)
    auto lo = __builtin_amdgcn_cvt_pk_f32_fp8((int)w, false);
    auto hi = __builtin_amdgcn_cvt_pk_f32_fp8((int)w, true);
    d[0] = lo[0]; d[1] = lo[1]; d[2] = hi[0]; d[3] = hi[1];
#else
#pragma unroll
    for (int i = 0; i < 4; ++i) {
        unsigned b = (w >> (8 * i)) & 0xffu;
        unsigned s = b >> 7, e = (b >> 3) & 15u, m = b & 7u;
        float v = e ? __uint_as_float(((e + 120u) << 23) | (m << 20))
                    : (float)m * 0.001953125f;
        d[i] = s ? -v : v;
    }
#endif
}

__device__ __forceinline__ void cast8(const float* __restrict__ src, unsigned short* __restrict__ dst, int i) {
    const float4* s = (const float4*)src + (size_t)i * 2;
    float4 a = s[0], b = s[1];
    uint4 o;
    o.x = (unsigned)f2bf(a.x) | ((unsigned)f2bf(a.y) << 16);
    o.y = (unsigned)f2bf(a.z) | ((unsigned)f2bf(a.w) << 16);
    o.z = (unsigned)f2bf(b.x) | ((unsigned)f2bf(b.y) << 16);
    o.w = (unsigned)f2bf(b.z) | ((unsigned)f2bf(b.w) << 16);
    *((uint4*)dst + i) = o;
}

// ---------------- K1: histogram + casts ----------------
// blocks [0,512): hist; [512,1536): cast x; [1536,1664): cast W (4 matrices)

__global__ __launch_bounds__(256) void prep_kernel(
        const int* __restrict__ q_id, int* __restrict__ count,
        const float* __restrict__ x, unsigned short* __restrict__ xb,
        const float* __restrict__ Wq, const float* __restrict__ Wk,
        const float* __restrict__ Wv, const float* __restrict__ Wx,
        unsigned short* __restrict__ Wb) {
    const int bid = blockIdx.x, tid = threadIdx.x;
    if (bid < 512) {
        atomicAdd(&count[q_id[bid * 256 + tid]], 1);
    } else if (bid < 1536) {
        cast8(x, xb, (bid - 512) * 256 + tid);
    } else {
        int idx = bid - 1536;
        int z = idx >> 5;
        const float* src = (z == 0) ? Wq : (z == 1) ? Wk : (z == 2) ? Wv : Wx;
        cast8(src, Wb + (size_t)z * (C_ * C_), (idx & 31) * 256 + tid);
    }
}

// ---------------- K2: scan (256 threads, 16 bins/thread) ----------------

__global__ __launch_bounds__(256) void scan_kernel(const int* __restrict__ count,
                                                   int* __restrict__ base,
                                                   int* __restrict__ cursor) {
    __shared__ int wsums[4];
    const int t = threadIdx.x, lane = t & 63, w = t >> 6;
    int c[16]; int s = 0;
#pragma unroll
    for (int i = 0; i < 16; ++i) { c[i] = count[t * 16 + i]; s += c[i]; }
    int x = s;
#pragma unroll
    for (int off = 1; off < 64; off <<= 1) {
        int y = __shfl_up(x, off);
        if (lane >= off) x += y;
    }
    if (lane == 63) wsums[w] = x;
    __syncthreads();
    if (t == 0) {
        int run = 0;
#pragma unroll
        for (int i = 0; i < 4; ++i) { int v = wsums[i]; wsums[i] = run; run += v; }
        base[S_] = run;
    }
    __syncthreads();
    int run = x - s + wsums[w];
#pragma unroll
    for (int i = 0; i < 16; ++i) {
        base[t * 16 + i] = run; cursor[t * 16 + i] = run; run += c[i];
    }
}

// ---------------- QKV gemm unit (weights-in-registers) ----------------
// u in [0,516) = 12 n-blocks x 43 m-groups. z: 0=q(bf16) 1=k(fp8) 2=v(bf16).

__device__ __forceinline__ void qkv_unit(
        int u, int tid,
        const unsigned short* __restrict__ xb, const unsigned short* __restrict__ Wb,
        const float* __restrict__ bq, const float* __restrict__ bk, const float* __restrict__ bv,
        unsigned short* __restrict__ qb, unsigned char* __restrict__ kf8,
        unsigned short* __restrict__ vb, unsigned short (*As)[264]) {
    const int nb = u % 12, mg = u / 12;
    const int lane = tid & 63, wave = tid >> 6;
    const int l16 = lane & 15, quad = lane >> 4;
    const int z = nb >> 2;
    const int colz = ((nb & 3) << 6) + (wave << 4);

    const unsigned short* Wrow = Wb + (size_t)z * (C_ * C_) + (size_t)(colz + l16) * C_;
    bf16x8_t breg[8];
#pragma unroll
    for (int ks = 0; ks < 8; ++ks)
        breg[ks] = *(const bf16x8_t*)(Wrow + ks * 32 + quad * 8);

    const float* bias = (z == 0) ? bq : (z == 1) ? bk : bv;
    const float bcol = bias[colz + l16];
    unsigned short* obb = (z == 0) ? qb : vb;
    const int ocol = colz + l16;

    const int c0 = (mg * 128) / 43, c1 = ((mg + 1) * 128) / 43;
    for (int c = c0; c < c1; ++c) {
        const int mbase = c * 64;
        __syncthreads();
#pragma unroll
        for (int it = 0; it < 8; ++it) {
            int l = it * 256 + tid;
            int r = l >> 5, cc = (l & 31) << 3;
            *(uint4*)&As[r][cc] = *(const uint4*)&xb[(size_t)(mbase + r) * C_ + cc];
        }
        __syncthreads();
#pragma unroll
        for (int mt = 0; mt < 4; ++mt) {
            f32x4_t acc = {0.f, 0.f, 0.f, 0.f};
#pragma unroll
            for (int ks = 0; ks < 8; ++ks) {
                bf16x8_t a = *(const bf16x8_t*)&As[mt * 16 + l16][ks * 32 + quad * 8];
                acc = __builtin_amdgcn_mfma_f32_16x16x32_bf16(a, breg[ks], acc, 0, 0, 0);
            }
            const int row0 = mbase + mt * 16 + quad * 4;
#pragma unroll
            for (int r = 0; r < 4; ++r) {
                float val = acc[r] + bcol;
                if (z == 1) kf8[(size_t)(row0 + r) * 256 + ocol] = f2fp8(val);
                else        obb[(size_t)(row0 + r) * 256 + ocol] = f2bf(val);
            }
        }
    }
}

// ---------------- K3: scatter + QKV GEMM ----------------

__global__ __launch_bounds__(256) void scatter_qkv_kernel(
        const int* __restrict__ q_id, const int* __restrict__ k_id,
        int* __restrict__ cursor, int* __restrict__ koff,
        const unsigned short* __restrict__ xb, const unsigned short* __restrict__ Wb,
        const float* __restrict__ bq, const float* __restrict__ bk, const float* __restrict__ bv,
        unsigned short* __restrict__ qb, unsigned char* __restrict__ kf8,
        unsigned short* __restrict__ vb) {
    __shared__ __align__(16) unsigned short As[64][264];
    const int bid = blockIdx.x, tid = threadIdx.x;
    if (bid < 512) {
        int e = bid * 256 + tid;
        int pos = atomicAdd(&cursor[q_id[e]], 1);
        koff[pos] = k_id[e] << 9;     // row-pair offset: kf8 bytes == vb elements
        return;
    }
    qkv_unit(bid - 512, tid, xb, Wb, bq, bk, bv, qb, kf8, vb, As);
}

// ---------------- K4: edge attention (phase-split, k-fp8 / v-bf16) ----------------
// One block per seq row s; 4 waves = 4 edge-parts. Lane: half=lane>>5 (batch),
// hl=lane&31 -> 8 channels; head = hl>>2; quad shfl for head dot.
// Per 64-edge chunk: Phase A reads only kf8 (2 MB, L2-resident) -> weights in
// registers; Phase B reads only vb (4 MB ~ L2) -> weighted accumulate.

__global__ __launch_bounds__(256) void attn_edge(
        const unsigned short* __restrict__ qb, const unsigned char* __restrict__ kf8,
        const unsigned short* __restrict__ vb,
        const int* __restrict__ base, const int* __restrict__ koff,
        unsigned short* __restrict__ attnb) {
    __shared__ float red[3][64][9];
    const int lane = threadIdx.x & 63;
    const int part = threadIdx.x >> 6;        // 0..3
    const int s = blockIdx.x;
    const int half = lane >> 5, hl = lane & 31;
    const int e0 = __builtin_amdgcn_readfirstlane(base[s]);
    const int e1 = __builtin_amdgcn_readfirstlane(base[s + 1]);

    const uint4 qq = *((const uint4*)(qb + (size_t)(s * 2 + half) * C_) + hl);
    const float q0 = bflo(qq.x), q1 = bfhi(qq.x), q2 = bflo(qq.y), q3 = bfhi(qq.y);
    const float q4 = bflo(qq.z), q5 = bfhi(qq.z), q6 = bflo(qq.w), q7 = bfhi(qq.w);

    float a0 = 0.f, a1 = 0.f, a2 = 0.f, a3 = 0.f, a4 = 0.f, a5 = 0.f, a6 = 0.f, a7 = 0.f;
    float wsum = 0.f;
    const float scale = 0.17677669529663687f;   // 1/sqrt(32)
    const int hoff = half * 256;

    for (int cb = e0; cb < e1; cb += 64) {
        const int m = min(64, e1 - cb);
        const int my = koff[cb + ((lane < m) ? lane : 0)];   // coalesced preload
        const int nt = (m > part) ? ((m - part + 3) >> 2) : 0;  // edges part,part+4,...
        float wreg[16];
        // ---- Phase A: scores from kf8 only ----
#pragma unroll
        for (int t = 0; t < 16; ++t) {
            wreg[t] = 0.f;
            if (t < nt) {
                const int o = __shfl(my, part + 4 * t);
                const uint2 kk = *(const uint2*)(kf8 + o + hoff + hl * 8);
                float kd[8];
                fp8x4_dec(kk.x, kd);
                fp8x4_dec(kk.y, kd + 4);
                float p = q0 * kd[0] + q1 * kd[1] + q2 * kd[2] + q3 * kd[3]
                        + q4 * kd[4] + q5 * kd[5] + q6 * kd[6] + q7 * kd[7];
                p += __shfl_xor(p, 1);
                p += __shfl_xor(p, 2);
                const float w = __expf(p * scale);
                wreg[t] = w;
                wsum += w;
            }
        }
        // ---- Phase B: weighted sum from vb only ----
#pragma unroll
        for (int t = 0; t < 16; ++t) {
            if (t < nt) {
                const int o = __shfl(my, part + 4 * t);
                const uint4 vv = *(const uint4*)(vb + o + hoff + hl * 8);
                const float w = wreg[t];
                a0 = fmaf(w, bflo(vv.x), a0); a1 = fmaf(w, bfhi(vv.x), a1);
                a2 = fmaf(w, bflo(vv.y), a2); a3 = fmaf(w, bfhi(vv.y), a3);
                a4 = fmaf(w, bflo(vv.z), a4); a5 = fmaf(w, bfhi(vv.z), a5);
                a6 = fmaf(w, bflo(vv.w), a6); a7 = fmaf(w, bfhi(vv.w), a7);
            }
        }
    }

    if (part) {
        float* r = &red[part - 1][lane][0];
        r[0] = a0; r[1] = a1; r[2] = a2; r[3] = a3;
        r[4] = a4; r[5] = a5; r[6] = a6; r[7] = a7; r[8] = wsum;
    }
    __syncthreads();
    if (part == 0) {
#pragma unroll
        for (int pp = 0; pp < 3; ++pp) {
            const float* r = &red[pp][lane][0];
            a0 += r[0]; a1 += r[1]; a2 += r[2]; a3 += r[3];
            a4 += r[4]; a5 += r[5]; a6 += r[6]; a7 += r[7]; wsum += r[8];
        }
        const float inv = 1.0f / wsum;
        uint4 o;
        o.x = (unsigned)f2bf(a0 * inv) | ((unsigned)f2bf(a1 * inv) << 16);
        o.y = (unsigned)f2bf(a2 * inv) | ((unsigned)f2bf(a3 * inv) << 16);
        o.z = (unsigned)f2bf(a4 * inv) | ((unsigned)f2bf(a5 * inv) << 16);
        o.w = (unsigned)f2bf(a6 * inv) | ((unsigned)f2bf(a7 * inv) << 16);
        *((uint4*)(attnb + (size_t)(s * 2 + half) * C_) + hl) = o;
    }
}

// ---------------- K5: output projection (weights-in-registers) ----------------

__global__ __launch_bounds__(256) void gemm_proj(
        const unsigned short* __restrict__ attnb, const unsigned short* __restrict__ Wxb,
        const float* __restrict__ bx, float* __restrict__ out) {
    __shared__ __align__(16) unsigned short As[64][264];
    const int tid = threadIdx.x;
    const int nb = blockIdx.x & 3, mg = blockIdx.x >> 2;
    const int lane = tid & 63, wave = tid >> 6;
    const int l16 = lane & 15, quad = lane >> 4;
    const int colz = (nb << 6) + (wave << 4);

    const unsigned short* Wrow = Wxb + (size_t)(colz + l16) * C_;
    bf16x8_t breg[8];
#pragma unroll
    for (int ks = 0; ks < 8; ++ks)
        breg[ks] = *(const bf16x8_t*)(Wrow + ks * 32 + quad * 8);
    const float bcol = bx[colz + l16];
    const int ocol = colz + l16;

    const int mbase = mg * 64;
#pragma unroll
    for (int it = 0; it < 8; ++it) {
        int l = it * 256 + tid;
        int r = l >> 5, cc = (l & 31) << 3;
        *(uint4*)&As[r][cc] = *(const uint4*)&attnb[(size_t)(mbase + r) * C_ + cc];
    }
    __syncthreads();
#pragma unroll
    for (int mt = 0; mt < 4; ++mt) {
        f32x4_t acc = {0.f, 0.f, 0.f, 0.f};
#pragma unroll
        for (int ks = 0; ks < 8; ++ks) {
            bf16x8_t a = *(const bf16x8_t*)&As[mt * 16 + l16][ks * 32 + quad * 8];
            acc = __builtin_amdgcn_mfma_f32_16x16x32_bf16(a, breg[ks], acc, 0, 0, 0);
        }
        const int row0 = mbase + mt * 16 + quad * 4;
#pragma unroll
        for (int r = 0; r < 4; ++r)
            out[(size_t)(row0 + r) * C_ + ocol] = acc[r] + bcol;
    }
}

// ---------------- launch ----------------

extern "C" void kernel_launch(void* const* d_in, const int* in_sizes, int n_in,
                              void* d_out, int out_size, void* d_ws, size_t ws_size,
                              hipStream_t stream) {
    const float* x  = (const float*)d_in[0];
    const int* q_id = (const int*)d_in[1];
    const int* k_id = (const int*)d_in[2];
    const float* Wq = (const float*)d_in[3];
    const float* bq = (const float*)d_in[4];
    const float* Wk = (const float*)d_in[5];
    const float* bk = (const float*)d_in[6];
    const float* Wv = (const float*)d_in[7];
    const float* bv = (const float*)d_in[8];
    const float* Wx = (const float*)d_in[9];
    const float* bx = (const float*)d_in[10];
    float* out = (float*)d_out;

    char* ws = (char*)d_ws;
    unsigned short* xb    = (unsigned short*)ws;   ws += (size_t)MR * C_ * 2;      // 4 MB
    unsigned short* qb    = (unsigned short*)ws;   ws += (size_t)MR * C_ * 2;      // 4 MB
    unsigned char*  kf8   = (unsigned char*)ws;    ws += (size_t)MR * C_;          // 2 MB
    unsigned short* vb    = (unsigned short*)ws;   ws += (size_t)MR * C_ * 2;      // 4 MB
    unsigned short* attnb = (unsigned short*)ws;   ws += (size_t)MR * C_ * 2;      // 4 MB
    unsigned short* Wb    = (unsigned short*)ws;   ws += (size_t)4 * C_ * C_ * 2;  // 512 KB
    int* count  = (int*)ws;                        ws += S_ * 4;
    int* base   = (int*)ws;                        ws += (S_ + 1) * 4;
    int* cursor = (int*)ws;                        ws += S_ * 4;
    int* koff   = (int*)ws;

    hipMemsetAsync(count, 0, S_ * sizeof(int), stream);
    prep_kernel<<<1664, 256, 0, stream>>>(q_id, count, x, xb, Wq, Wk, Wv, Wx, Wb);
    scan_kernel<<<1, 256, 0, stream>>>(count, base, cursor);
    scatter_qkv_kernel<<<1028, 256, 0, stream>>>(q_id, k_id, cursor, koff,
                                                 xb, Wb, bq, bk, bv, qb, kf8, vb);
    attn_edge<<<S_, 256, 0, stream>>>(qb, kf8, vb, base, koff, attnb);
    gemm_proj<<<512, 256, 0, stream>>>(attnb, Wb + (size_t)3 * C_ * C_, bx, out);
}

// Round 9
// 148.087 us; speedup vs baseline: 2.6969x; 1.0019x over previous
//
#include <hip/hip_runtime.h>

// Problem constants (fixed by the dataset)
constexpr int S_  = 4096;
constexpr int B_  = 2;
constexpr int C_  = 256;
constexpr int H_  = 8;
constexpr int E_  = 131072;
constexpr int CC_ = 32;
constexpr int MR  = S_ * B_;   // 8192 rows for all GEMMs

typedef __attribute__((ext_vector_type(8))) short bf16x8_t;
typedef __attribute__((ext_vector_type(4))) float f32x4_t;

__device__ __forceinline__ unsigned short f2bf(float f) {
    unsigned int u = __float_as_uint(f);
    u += 0x7fffu + ((u >> 16) & 1u);   // round-to-nearest-even
    return (unsigned short)(u >> 16);
}
__device__ __forceinline__ float bflo(unsigned int u) { return __uint_as_float(u << 16); }
__device__ __forceinline__ float bfhi(unsigned int u) { return __uint_as_float(u & 0xffff0000u); }

__device__ __forceinline__ void cast8(const float* __restrict__ src, unsigned short* __restrict__ dst, int i) {
    const float4* s = (const float4*)src + (size_t)i * 2;
    float4 a = s[0], b = s[1];
    uint4 o;
    o.x = (unsigned)f2bf(a.x) | ((unsigned)f2bf(a.y) << 16);
    o.y = (unsigned)f2bf(a.z) | ((unsigned)f2bf(a.w) << 16);
    o.z = (unsigned)f2bf(b.x) | ((unsigned)f2bf(b.y) << 16);
    o.w = (unsigned)f2bf(b.z) | ((unsigned)f2bf(b.w) << 16);
    *((uint4*)dst + i) = o;
}

// ---------------- K1: histogram + casts ----------------
// blocks [0,512): hist; [512,1536): cast x; [1536,1664): cast W (4 matrices)

__global__ __launch_bounds__(256) void prep_kernel(
        const int* __restrict__ q_id, int* __restrict__ count,
        const float* __restrict__ x, unsigned short* __restrict__ xb,
        const float* __restrict__ Wq, const float* __restrict__ Wk,
        const float* __restrict__ Wv, const float* __restrict__ Wx,
        unsigned short* __restrict__ Wb) {
    const int bid = blockIdx.x, tid = threadIdx.x;
    if (bid < 512) {
        atomicAdd(&count[q_id[bid * 256 + tid]], 1);
    } else if (bid < 1536) {
        cast8(x, xb, (bid - 512) * 256 + tid);
    } else {
        int idx = bid - 1536;
        int z = idx >> 5;
        const float* src = (z == 0) ? Wq : (z == 1) ? Wk : (z == 2) ? Wv : Wx;
        cast8(src, Wb + (size_t)z * (C_ * C_), (idx & 31) * 256 + tid);
    }
}

// ---------------- K2: scan ----------------

__global__ __launch_bounds__(1024) void scan_kernel(const int* __restrict__ count,
                                                    int* __restrict__ base,
                                                    int* __restrict__ cursor) {
    __shared__ int wsums[16];
    const int t = threadIdx.x, lane = t & 63, w = t >> 6;
    int c0 = count[4 * t + 0], c1 = count[4 * t + 1];
    int c2 = count[4 * t + 2], c3 = count[4 * t + 3];
    int tsum = c0 + c1 + c2 + c3;
    int x = tsum;
#pragma unroll
    for (int off = 1; off < 64; off <<= 1) {
        int y = __shfl_up(x, off);
        if (lane >= off) x += y;
    }
    if (lane == 63) wsums[w] = x;
    __syncthreads();
    if (t == 0) {
        int run = 0;
#pragma unroll
        for (int i = 0; i < 16; ++i) { int v = wsums[i]; wsums[i] = run; run += v; }
        base[S_] = run;
    }
    __syncthreads();
    int excl = x - tsum + wsums[w];
    int b0 = excl, b1 = b0 + c0, b2 = b1 + c1, b3 = b2 + c2;
    base[4 * t + 0] = b0; base[4 * t + 1] = b1;
    base[4 * t + 2] = b2; base[4 * t + 3] = b3;
    cursor[4 * t + 0] = b0; cursor[4 * t + 1] = b1;
    cursor[4 * t + 2] = b2; cursor[4 * t + 3] = b3;
}

// ---------------- K3: scatter + QKV GEMM (weights-in-registers) ----------------
// blocks [0,512): scatter. blocks [512,1028): gemm — 12 n-blocks (64 cols of
// N=768 across q,k,v) x 43 m-groups. Per wave: B-strip 16x256 in 32 VGPRs,
// A staged 64 rows x K=256 in LDS, C/D frags stored directly (no LDS epilogue).

__global__ __launch_bounds__(256) void scatter_qkv_kernel(
        const int* __restrict__ q_id, const int* __restrict__ k_id,
        int* __restrict__ cursor, int* __restrict__ koff_sorted,
        const unsigned short* __restrict__ xb, const unsigned short* __restrict__ Wb,
        const float* __restrict__ bq, const float* __restrict__ bk, const float* __restrict__ bv,
        unsigned short* __restrict__ qb, unsigned short* __restrict__ kvb) {
    __shared__ __align__(16) unsigned short As[64][264];   // 33 KB, +8 pad
    const int bid = blockIdx.x, tid = threadIdx.x;
    if (bid < 512) {
        int e = bid * 256 + tid;
        int pos = atomicAdd(&cursor[q_id[e]], 1);
        koff_sorted[pos] = k_id[e] << 10;          // element offset into kvb
        return;
    }
    const int u = bid - 512;                       // 0..515
    const int nb = u % 12, mg = u / 12;            // n-block, m-group (0..42)
    const int lane = tid & 63, wave = tid >> 6;
    const int l16 = lane & 15, quad = lane >> 4;
    const int z = nb >> 2;                         // 0=q 1=k 2=v
    const int colz = ((nb & 3) << 6) + (wave << 4);

    // B-strip: W rows [colz, colz+16), full K, in registers
    const unsigned short* Wrow = Wb + (size_t)z * (C_ * C_) + (size_t)(colz + l16) * C_;
    bf16x8_t breg[8];
#pragma unroll
    for (int ks = 0; ks < 8; ++ks)
        breg[ks] = *(const bf16x8_t*)(Wrow + ks * 32 + quad * 8);

    const float* bias = (z == 0) ? bq : (z == 1) ? bk : bv;
    const float bcol = bias[colz + l16];
    unsigned short* ob = (z == 0) ? qb : kvb;
    const int ostr = (z == 0) ? 256 : 512;
    const int ocol = ((z == 2) ? 256 : 0) + colz + l16;

    const int c0 = (mg * 128) / 43, c1 = ((mg + 1) * 128) / 43;
    for (int c = c0; c < c1; ++c) {
        const int mbase = c * 64;
        __syncthreads();
#pragma unroll
        for (int it = 0; it < 8; ++it) {
            int l = it * 256 + tid;
            int r = l >> 5, cc = (l & 31) << 3;
            *(uint4*)&As[r][cc] = *(const uint4*)&xb[(size_t)(mbase + r) * C_ + cc];
        }
        __syncthreads();
#pragma unroll
        for (int mt = 0; mt < 4; ++mt) {
            f32x4_t acc = {0.f, 0.f, 0.f, 0.f};
#pragma unroll
            for (int ks = 0; ks < 8; ++ks) {
                bf16x8_t a = *(const bf16x8_t*)&As[mt * 16 + l16][ks * 32 + quad * 8];
                acc = __builtin_amdgcn_mfma_f32_16x16x32_bf16(a, breg[ks], acc, 0, 0, 0);
            }
            const int row0 = mbase + mt * 16 + quad * 4;
#pragma unroll
            for (int r = 0; r < 4; ++r)
                ob[(size_t)(row0 + r) * ostr + ocol] = f2bf(acc[r] + bcol);
        }
    }
}

// ---------------- K4: edge attention (pipelined gather) ----------------
// Block = 4 waves = 2 seq rows x 2 edge-parts. Wave covers both batch slices
// (lanes 0-31 -> b=0, 32-63 -> b=1), 8 bf16 channels/lane; head dot = quad shfl.
// Per 64-edge chunk: coalesced per-lane koff preload + readlane broadcast;
// 2-slot software pipeline keeps 2 gathers in flight per wave.

__global__ __launch_bounds__(256) void attn_edge(
        const unsigned short* __restrict__ qb, const unsigned short* __restrict__ kvb,
        const int* __restrict__ base, const int* __restrict__ koff,
        unsigned short* __restrict__ attnb) {
    __shared__ float red[2][64][9];
    const int lane = threadIdx.x & 63;
    const int wave = threadIdx.x >> 6;
    const int rw = wave >> 1, part = wave & 1;
    const int s = blockIdx.x * 2 + rw;
    const int half = lane >> 5, hl = lane & 31;
    const int e0 = __builtin_amdgcn_readfirstlane(base[s]);
    const int e1 = __builtin_amdgcn_readfirstlane(base[s + 1]);

    const uint4 qq = *((const uint4*)(qb + (size_t)(s * 2 + half) * C_) + hl);
    const float q0 = bflo(qq.x), q1 = bfhi(qq.x), q2 = bflo(qq.y), q3 = bfhi(qq.y);
    const float q4 = bflo(qq.z), q5 = bfhi(qq.z), q6 = bflo(qq.w), q7 = bfhi(qq.w);

    float a0 = 0.f, a1 = 0.f, a2 = 0.f, a3 = 0.f, a4 = 0.f, a5 = 0.f, a6 = 0.f, a7 = 0.f;
    float wsum = 0.f;
    const float scale = 0.17677669529663687f;   // 1/sqrt(32)

    auto edge = [&](const uint4& kk, const uint4& vv) {
        float p = q0 * bflo(kk.x) + q1 * bfhi(kk.x)
                + q2 * bflo(kk.y) + q3 * bfhi(kk.y)
                + q4 * bflo(kk.z) + q5 * bfhi(kk.z)
                + q6 * bflo(kk.w) + q7 * bfhi(kk.w);
        p += __shfl_xor(p, 1);
        p += __shfl_xor(p, 2);
        const float w = __expf(p * scale);
        a0 = fmaf(w, bflo(vv.x), a0); a1 = fmaf(w, bfhi(vv.x), a1);
        a2 = fmaf(w, bflo(vv.y), a2); a3 = fmaf(w, bfhi(vv.y), a3);
        a4 = fmaf(w, bflo(vv.z), a4); a5 = fmaf(w, bfhi(vv.z), a5);
        a6 = fmaf(w, bflo(vv.w), a6); a7 = fmaf(w, bfhi(vv.w), a7);
        wsum += w;
    };
    auto fetch = [&](int my, int t, uint4& kk, uint4& vv) {
        int o = __builtin_amdgcn_readlane(my, part + 2 * t);
        const uint4* p = (const uint4*)(kvb + o + half * 512);
        kk = p[hl]; vv = p[32 + hl];
    };

    for (int b0 = e0; b0 < e1; b0 += 64) {
        const int m = min(64, e1 - b0);
        const int my = koff[b0 + ((lane < m) ? lane : 0)];
        const int nm = (m > part) ? ((m - part + 1) >> 1) : 0;
        uint4 kka = {}, vva = {}, kkb = {}, vvb = {};
        if (nm > 0) fetch(my, 0, kka, vva);
        if (nm > 1) fetch(my, 1, kkb, vvb);
        int t = 0;
        for (; t + 3 < nm; t += 2) {
            edge(kka, vva);
            fetch(my, t + 2, kka, vva);
            edge(kkb, vvb);
            fetch(my, t + 3, kkb, vvb);
        }
        if (t < nm)     edge(kka, vva);
        if (t + 1 < nm) edge(kkb, vvb);
        if (t + 2 < nm) { fetch(my, t + 2, kka, vva); edge(kka, vva); }
    }

    if (part == 1) {
        float* r = red[rw][lane];
        r[0] = a0; r[1] = a1; r[2] = a2; r[3] = a3;
        r[4] = a4; r[5] = a5; r[6] = a6; r[7] = a7; r[8] = wsum;
    }
    __syncthreads();
    if (part == 0) {
        const float* r = red[rw][lane];
        a0 += r[0]; a1 += r[1]; a2 += r[2]; a3 += r[3];
        a4 += r[4]; a5 += r[5]; a6 += r[6]; a7 += r[7]; wsum += r[8];
        const float inv = 1.0f / wsum;
        uint4 o;
        o.x = (unsigned)f2bf(a0 * inv) | ((unsigned)f2bf(a1 * inv) << 16);
        o.y = (unsigned)f2bf(a2 * inv) | ((unsigned)f2bf(a3 * inv) << 16);
        o.z = (unsigned)f2bf(a4 * inv) | ((unsigned)f2bf(a5 * inv) << 16);
        o.w = (unsigned)f2bf(a6 * inv) | ((unsigned)f2bf(a7 * inv) << 16);
        *((uint4*)(attnb + (size_t)(s * 2 + half) * C_) + hl) = o;
    }
}

// ---------------- K5: output projection (weights-in-registers) ----------------
// 512 blocks = 4 n-blocks x 128 m-groups (one 64-row chunk each). fp32 out.

__global__ __launch_bounds__(256) void gemm_proj(
        const unsigned short* __restrict__ attnb, const unsigned short* __restrict__ Wxb,
        const float* __restrict__ bx, float* __restrict__ out) {
    __shared__ __align__(16) unsigned short As[64][264];
    const int tid = threadIdx.x;
    const int nb = blockIdx.x & 3, mg = blockIdx.x >> 2;
    const int lane = tid & 63, wave = tid >> 6;
    const int l16 = lane & 15, quad = lane >> 4;
    const int colz = (nb << 6) + (wave << 4);

    const unsigned short* Wrow = Wxb + (size_t)(colz + l16) * C_;
    bf16x8_t breg[8];
#pragma unroll
    for (int ks = 0; ks < 8; ++ks)
        breg[ks] = *(const bf16x8_t*)(Wrow + ks * 32 + quad * 8);
    const float bcol = bx[colz + l16];
    const int ocol = colz + l16;

    const int mbase = mg * 64;
#pragma unroll
    for (int it = 0; it < 8; ++it) {
        int l = it * 256 + tid;
        int r = l >> 5, cc = (l & 31) << 3;
        *(uint4*)&As[r][cc] = *(const uint4*)&attnb[(size_t)(mbase + r) * C_ + cc];
    }
    __syncthreads();
#pragma unroll
    for (int mt = 0; mt < 4; ++mt) {
        f32x4_t acc = {0.f, 0.f, 0.f, 0.f};
#pragma unroll
        for (int ks = 0; ks < 8; ++ks) {
            bf16x8_t a = *(const bf16x8_t*)&As[mt * 16 + l16][ks * 32 + quad * 8];
            acc = __builtin_amdgcn_mfma_f32_16x16x32_bf16(a, breg[ks], acc, 0, 0, 0);
        }
        const int row0 = mbase + mt * 16 + quad * 4;
#pragma unroll
        for (int r = 0; r < 4; ++r)
            out[(size_t)(row0 + r) * C_ + ocol] = acc[r] + bcol;
    }
}

// ---------------- launch ----------------

extern "C" void kernel_launch(void* const* d_in, const int* in_sizes, int n_in,
                              void* d_out, int out_size, void* d_ws, size_t ws_size,
                              hipStream_t stream) {
    const float* x  = (const float*)d_in[0];
    const int* q_id = (const int*)d_in[1];
    const int* k_id = (const int*)d_in[2];
    const float* Wq = (const float*)d_in[3];
    const float* bq = (const float*)d_in[4];
    const float* Wk = (const float*)d_in[5];
    const float* bk = (const float*)d_in[6];
    const float* Wv = (const float*)d_in[7];
    const float* bv = (const float*)d_in[8];
    const float* Wx = (const float*)d_in[9];
    const float* bx = (const float*)d_in[10];
    float* out = (float*)d_out;

    char* ws = (char*)d_ws;
    unsigned short* xb    = (unsigned short*)ws;                 ws += (size_t)MR * C_ * 2;
    unsigned short* qb    = (unsigned short*)ws;                 ws += (size_t)MR * C_ * 2;
    unsigned short* kvb   = (unsigned short*)ws;                 ws += (size_t)MR * 512 * 2;
    unsigned short* attnb = (unsigned short*)ws;                 ws += (size_t)MR * C_ * 2;
    unsigned short* Wb    = (unsigned short*)ws;                 ws += (size_t)4 * C_ * C_ * 2;
    int* count       = (int*)ws;                                 ws += S_ * 4;
    int* base        = (int*)ws;                                 ws += (S_ + 1) * 4;
    int* cursor      = (int*)ws;                                 ws += S_ * 4;
    int* koff_sorted = (int*)ws;

    hipMemsetAsync(count, 0, S_ * sizeof(int), stream);
    prep_kernel<<<1664, 256, 0, stream>>>(q_id, count, x, xb, Wq, Wk, Wv, Wx, Wb);
    scan_kernel<<<1, 1024, 0, stream>>>(count, base, cursor);
    scatter_qkv_kernel<<<1028, 256, 0, stream>>>(q_id, k_id, cursor, koff_sorted,
                                                 xb, Wb, bq, bk, bv, qb, kvb);
    attn_edge<<<S_ / 2, 256, 0, stream>>>(qb, kvb, base, koff_sorted, attnb);
    gemm_proj<<<512, 256, 0, stream>>>(attnb, Wb + (size_t)3 * C_ * C_, bx, out);
}